// Round 1
// baseline (2180.148 us; speedup 1.0000x reference)
//
#include <hip/hip_runtime.h>

#define N_USER 100000
#define N_ITEM 200000
#define N_TOT  (N_USER + N_ITEM)
#define D      64

// K1: out[i][d] = emb[i][d] + sum_k w[i][k] * emb_side[nb[i][k]][d]
// one 64-lane wave per row, lane = d.
__global__ __launch_bounds__(256) void base_neighbor_kernel(
    const float* __restrict__ users, const float* __restrict__ items,
    const int*   __restrict__ unb,   const float* __restrict__ uw,
    const int*   __restrict__ inb,   const float* __restrict__ iw,
    float* __restrict__ out)
{
    int gtid = blockIdx.x * blockDim.x + threadIdx.x;
    int row  = gtid >> 6;          // wave id
    int lane = gtid & 63;          // d
    if (row >= N_TOT) return;

    float acc;
    if (row < N_USER) {
        acc = users[(size_t)row * D + lane];
        const int*   nb = unb + (size_t)row * 10;
        const float* w  = uw  + (size_t)row * 10;
        #pragma unroll
        for (int k = 0; k < 10; ++k) {
            acc += w[k] * users[(size_t)nb[k] * D + lane];
        }
    } else {
        int r = row - N_USER;
        acc = items[(size_t)r * D + lane];
        const int*   nb = inb + (size_t)r * 10;
        const float* w  = iw  + (size_t)r * 10;
        #pragma unroll
        for (int k = 0; k < 10; ++k) {
            acc += w[k] * items[(size_t)nb[k] * D + lane];
        }
    }
    out[(size_t)row * D + lane] = acc;
}

// K2: for each edge e: out[rows[e]][d] += vals[e] * emb[cols[e]][d]
// one 64-lane wave per edge, lane = d. emb is the ORIGINAL concat(users, items).
__global__ __launch_bounds__(256) void edge_scatter_kernel(
    const float* __restrict__ users, const float* __restrict__ items,
    const int*   __restrict__ rows,  const int* __restrict__ cols,
    const float* __restrict__ vals,
    float* __restrict__ out, int nnz)
{
    int gtid = blockIdx.x * blockDim.x + threadIdx.x;
    int e    = gtid >> 6;
    int lane = gtid & 63;
    if (e >= nnz) return;

    int   r = rows[e];
    int   c = cols[e];
    float v = vals[e];

    const float* src = (c < N_USER) ? (users + (size_t)c * D)
                                    : (items + (size_t)(c - N_USER) * D);
    atomicAdd(&out[(size_t)r * D + lane], v * src[lane]);
}

extern "C" void kernel_launch(void* const* d_in, const int* in_sizes, int n_in,
                              void* d_out, int out_size, void* d_ws, size_t ws_size,
                              hipStream_t stream) {
    const float* users = (const float*)d_in[0];
    const float* items = (const float*)d_in[1];
    const int*   unb   = (const int*)  d_in[2];
    const float* uw    = (const float*)d_in[3];
    const int*   inb   = (const int*)  d_in[4];
    const float* iw    = (const float*)d_in[5];
    const int*   grow  = (const int*)  d_in[6];
    const int*   gcol  = (const int*)  d_in[7];
    const float* gval  = (const float*)d_in[8];
    float* out = (float*)d_out;

    const int nnz = in_sizes[6];

    // K1: one wave per row -> N_TOT*64 threads
    {
        long long threads = (long long)N_TOT * 64;
        int block = 256;
        int grid  = (int)((threads + block - 1) / block);
        base_neighbor_kernel<<<grid, block, 0, stream>>>(users, items, unb, uw, inb, iw, out);
    }
    // K2: one wave per edge -> nnz*64 threads
    {
        long long threads = (long long)nnz * 64;
        int block = 256;
        long long grid = (threads + block - 1) / block;
        edge_scatter_kernel<<<(int)grid, block, 0, stream>>>(users, items, grow, gcol, gval, out, nnz);
    }
}

// Round 2
// 1409.547 us; speedup vs baseline: 1.5467x; 1.5467x over previous
//
#include <hip/hip_runtime.h>

#define N_USER 100000
#define N_ITEM 200000
#define N_TOT  (N_USER + N_ITEM)
#define D      64
#define SCAN_CHUNK 2048   // 256 threads x 8 elems

// ---------- CSR build ----------

__global__ void count_kernel(const int* __restrict__ rows, int* __restrict__ cnt, int nnz) {
    int i = blockIdx.x * blockDim.x + threadIdx.x;
    int stride = gridDim.x * blockDim.x;
    for (; i < nnz; i += stride) atomicAdd(&cnt[rows[i]], 1);
}

__global__ void scan_block_sums(const int* __restrict__ cnt, int* __restrict__ bsum, int n) {
    __shared__ int sdata[256];
    int base = blockIdx.x * SCAN_CHUNK;
    int s = 0;
    for (int t = threadIdx.x; t < SCAN_CHUNK; t += 256) {
        int idx = base + t;
        s += (idx < n) ? cnt[idx] : 0;
    }
    sdata[threadIdx.x] = s;
    __syncthreads();
    for (int off = 128; off > 0; off >>= 1) {
        if (threadIdx.x < off) sdata[threadIdx.x] += sdata[threadIdx.x + off];
        __syncthreads();
    }
    if (threadIdx.x == 0) bsum[blockIdx.x] = sdata[0];
}

__global__ void scan_bsum_kernel(int* __restrict__ bsum, int nb) {
    if (threadIdx.x == 0 && blockIdx.x == 0) {
        int acc = 0;
        for (int i = 0; i < nb; ++i) { int v = bsum[i]; bsum[i] = acc; acc += v; }
    }
}

__global__ void scan_final(const int* __restrict__ cnt, const int* __restrict__ bsum,
                           int* __restrict__ row_start, int n, int nnz) {
    __shared__ int sums[256];
    int b = blockIdx.x, t = threadIdx.x;
    int base = b * SCAN_CHUNK;
    int loc[8];
    int s = 0;
    #pragma unroll
    for (int k = 0; k < 8; ++k) {
        int idx = base + t * 8 + k;
        int v = (idx < n) ? cnt[idx] : 0;
        loc[k] = s; s += v;
    }
    sums[t] = s;
    __syncthreads();
    // inclusive Hillis-Steele scan over 256 per-thread sums
    for (int off = 1; off < 256; off <<= 1) {
        int v = (t >= off) ? sums[t - off] : 0;
        __syncthreads();
        sums[t] += v;
        __syncthreads();
    }
    int off0 = bsum[b] + (sums[t] - s);   // exclusive offset for this thread's run
    #pragma unroll
    for (int k = 0; k < 8; ++k) {
        int idx = base + t * 8 + k;
        if (idx < n) row_start[idx] = off0 + loc[k];
    }
    if (b == gridDim.x - 1 && t == 255) row_start[n] = nnz;
}

__global__ void fill_kernel(const int* __restrict__ rows, const int* __restrict__ cols,
                            const float* __restrict__ vals, const int* __restrict__ row_start,
                            int* __restrict__ pos, uint2* __restrict__ eg, int nnz) {
    int i = blockIdx.x * blockDim.x + threadIdx.x;
    int stride = gridDim.x * blockDim.x;
    for (; i < nnz; i += stride) {
        int r = rows[i];
        int p = atomicAdd(&pos[r], 1);
        uint2 e;
        e.x = (unsigned)cols[i];
        e.y = __float_as_uint(vals[i]);
        eg[row_start[r] + p] = e;
    }
}

// ---------- fused gather: base + neighbor + segment_sum ----------
// one 64-lane wave per row, lane = d.
__global__ __launch_bounds__(256) void gather_kernel(
    const float* __restrict__ users, const float* __restrict__ items,
    const int*   __restrict__ unb,   const float* __restrict__ uw,
    const int*   __restrict__ inb,   const float* __restrict__ iw,
    const int*   __restrict__ row_start, const uint2* __restrict__ eg,
    float* __restrict__ out)
{
    int gtid = blockIdx.x * blockDim.x + threadIdx.x;
    int row  = gtid >> 6;
    int lane = gtid & 63;
    if (row >= N_TOT) return;

    float acc;
    if (row < N_USER) {
        acc = users[(size_t)row * D + lane];
        const int*   nb = unb + (size_t)row * 10;
        const float* w  = uw  + (size_t)row * 10;
        #pragma unroll
        for (int k = 0; k < 10; ++k) acc += w[k] * users[(size_t)nb[k] * D + lane];
    } else {
        int r = row - N_USER;
        acc = items[(size_t)r * D + lane];
        const int*   nb = inb + (size_t)r * 10;
        const float* w  = iw  + (size_t)r * 10;
        #pragma unroll
        for (int k = 0; k < 10; ++k) acc += w[k] * items[(size_t)nb[k] * D + lane];
    }

    int s = row_start[row];
    int e = row_start[row + 1];
    int i = s;
    for (; i + 3 < e; i += 4) {
        uint2 e0 = eg[i], e1 = eg[i + 1], e2 = eg[i + 2], e3 = eg[i + 3];
        int c0 = (int)e0.x, c1 = (int)e1.x, c2 = (int)e2.x, c3 = (int)e3.x;
        const float* s0 = (c0 < N_USER) ? users + (size_t)c0 * D : items + (size_t)(c0 - N_USER) * D;
        const float* s1 = (c1 < N_USER) ? users + (size_t)c1 * D : items + (size_t)(c1 - N_USER) * D;
        const float* s2 = (c2 < N_USER) ? users + (size_t)c2 * D : items + (size_t)(c2 - N_USER) * D;
        const float* s3 = (c3 < N_USER) ? users + (size_t)c3 * D : items + (size_t)(c3 - N_USER) * D;
        float v0 = s0[lane], v1 = s1[lane], v2 = s2[lane], v3 = s3[lane];
        acc += __uint_as_float(e0.y) * v0;
        acc += __uint_as_float(e1.y) * v1;
        acc += __uint_as_float(e2.y) * v2;
        acc += __uint_as_float(e3.y) * v3;
    }
    for (; i < e; ++i) {
        uint2 ed = eg[i];
        int c = (int)ed.x;
        const float* src = (c < N_USER) ? users + (size_t)c * D : items + (size_t)(c - N_USER) * D;
        acc += __uint_as_float(ed.y) * src[lane];
    }

    out[(size_t)row * D + lane] = acc;
}

// ---------- fallback (round-1) scatter path ----------
__global__ __launch_bounds__(256) void base_neighbor_kernel(
    const float* __restrict__ users, const float* __restrict__ items,
    const int*   __restrict__ unb,   const float* __restrict__ uw,
    const int*   __restrict__ inb,   const float* __restrict__ iw,
    float* __restrict__ out)
{
    int gtid = blockIdx.x * blockDim.x + threadIdx.x;
    int row  = gtid >> 6;
    int lane = gtid & 63;
    if (row >= N_TOT) return;
    float acc;
    if (row < N_USER) {
        acc = users[(size_t)row * D + lane];
        const int*   nb = unb + (size_t)row * 10;
        const float* w  = uw  + (size_t)row * 10;
        #pragma unroll
        for (int k = 0; k < 10; ++k) acc += w[k] * users[(size_t)nb[k] * D + lane];
    } else {
        int r = row - N_USER;
        acc = items[(size_t)r * D + lane];
        const int*   nb = inb + (size_t)r * 10;
        const float* w  = iw  + (size_t)r * 10;
        #pragma unroll
        for (int k = 0; k < 10; ++k) acc += w[k] * items[(size_t)nb[k] * D + lane];
    }
    out[(size_t)row * D + lane] = acc;
}

__global__ __launch_bounds__(256) void edge_scatter_kernel(
    const float* __restrict__ users, const float* __restrict__ items,
    const int*   __restrict__ rows,  const int* __restrict__ cols,
    const float* __restrict__ vals,
    float* __restrict__ out, int nnz)
{
    int gtid = blockIdx.x * blockDim.x + threadIdx.x;
    int e    = gtid >> 6;
    int lane = gtid & 63;
    if (e >= nnz) return;
    int   r = rows[e];
    int   c = cols[e];
    float v = vals[e];
    const float* src = (c < N_USER) ? (users + (size_t)c * D)
                                    : (items + (size_t)(c - N_USER) * D);
    atomicAdd(&out[(size_t)r * D + lane], v * src[lane]);
}

extern "C" void kernel_launch(void* const* d_in, const int* in_sizes, int n_in,
                              void* d_out, int out_size, void* d_ws, size_t ws_size,
                              hipStream_t stream) {
    const float* users = (const float*)d_in[0];
    const float* items = (const float*)d_in[1];
    const int*   unb   = (const int*)  d_in[2];
    const float* uw    = (const float*)d_in[3];
    const int*   inb   = (const int*)  d_in[4];
    const float* iw    = (const float*)d_in[5];
    const int*   grow  = (const int*)  d_in[6];
    const int*   gcol  = (const int*)  d_in[7];
    const float* gval  = (const float*)d_in[8];
    float* out = (float*)d_out;

    const int nnz = in_sizes[6];

    // workspace layout (256B-aligned chunks)
    const size_t sz_row_start = ((size_t)(N_TOT + 1) * 4 + 255) & ~(size_t)255;
    const size_t sz_cnt       = ((size_t)N_TOT * 4 + 255) & ~(size_t)255;
    const int    nb_blocks    = (N_TOT + SCAN_CHUNK - 1) / SCAN_CHUNK;
    const size_t sz_bsum      = ((size_t)nb_blocks * 4 + 255) & ~(size_t)255;
    const size_t sz_eg        = (size_t)nnz * 8;
    const size_t need         = sz_row_start + sz_cnt + sz_bsum + sz_eg;

    if (ws_size >= need) {
        char* wsp = (char*)d_ws;
        int*   row_start = (int*)wsp;                       wsp += sz_row_start;
        int*   cnt       = (int*)wsp;                       wsp += sz_cnt;
        int*   bsum      = (int*)wsp;                       wsp += sz_bsum;
        uint2* eg        = (uint2*)wsp;

        hipMemsetAsync(cnt, 0, (size_t)N_TOT * 4, stream);
        count_kernel<<<2048, 256, 0, stream>>>(grow, cnt, nnz);
        scan_block_sums<<<nb_blocks, 256, 0, stream>>>(cnt, bsum, N_TOT);
        scan_bsum_kernel<<<1, 64, 0, stream>>>(bsum, nb_blocks);
        scan_final<<<nb_blocks, 256, 0, stream>>>(cnt, bsum, row_start, N_TOT, nnz);
        hipMemsetAsync(cnt, 0, (size_t)N_TOT * 4, stream);   // reuse as pos[]
        fill_kernel<<<2048, 256, 0, stream>>>(grow, gcol, gval, row_start, cnt, eg, nnz);

        long long threads = (long long)N_TOT * 64;
        int grid = (int)((threads + 255) / 256);
        gather_kernel<<<grid, 256, 0, stream>>>(users, items, unb, uw, inb, iw,
                                                row_start, eg, out);
    } else {
        // fallback: scatter with atomics
        long long threads = (long long)N_TOT * 64;
        int grid = (int)((threads + 255) / 256);
        base_neighbor_kernel<<<grid, 256, 0, stream>>>(users, items, unb, uw, inb, iw, out);
        long long ethreads = (long long)nnz * 64;
        long long egrid = (ethreads + 255) / 256;
        edge_scatter_kernel<<<(int)egrid, 256, 0, stream>>>(users, items, grow, gcol, gval, out, nnz);
    }
}